// Round 4
// baseline (653.573 us; speedup 1.0000x reference)
//
#include <hip/hip_runtime.h>
#include <hip/hip_bf16.h>
#include <stdint.h>

// Problem constants
#define DD 1024
#define AA 128
#define HH 8
#define FF 4096
#define BB 4
#define SS 2048
#define MM (BB*SS)      // 8192 tokens
#define EPSV 1e-5f

typedef __bf16 bf16x8 __attribute__((ext_vector_type(8)));
typedef __bf16 bf16x4 __attribute__((ext_vector_type(4)));
typedef float  f32x4  __attribute__((ext_vector_type(4)));
typedef float  f32x16 __attribute__((ext_vector_type(16)));

// ---------------- async global->LDS (16B per lane) ----------------
__device__ __forceinline__ void gload_lds16(const void* g, void* l) {
  __builtin_amdgcn_global_load_lds(
      (const __attribute__((address_space(1))) uint32_t*)(uintptr_t)g,
      (__attribute__((address_space(3))) uint32_t*)(uintptr_t)l, 16, 0, 0);
}

// ---------------- transpose + f32->bf16 convert: out[c][r] = in[r][c] ----------------
__global__ __launch_bounds__(256) void transpose_conv(const float* __restrict__ in,
                                                      __bf16* __restrict__ out,
                                                      int rows, int cols) {
  __shared__ float tile[64][65];
  const int r0 = blockIdx.y * 64, c0 = blockIdx.x * 64;
  for (int i = threadIdx.x; i < 4096; i += 256) {
    int r = i >> 6, c = i & 63;
    tile[r][c] = in[(long)(r0 + r) * cols + c0 + c];
  }
  __syncthreads();
  for (int i = threadIdx.x; i < 4096; i += 256) {
    int c = i >> 6, r = i & 63;
    out[(long)(c0 + c) * rows + r0 + r] = (__bf16)tile[r][c];
  }
}

// QKV weights: Wq/Wk/Wv are [H][D][A]; build WqkvT [3072][1024] (row n = p*1024+h*128+a, col d)
__global__ __launch_bounds__(256) void transpose_qkv(const float* __restrict__ Wq,
                                                     const float* __restrict__ Wk,
                                                     const float* __restrict__ Wv,
                                                     __bf16* __restrict__ out) {
  __shared__ float tile[64][65];
  const int z = blockIdx.z;
  const int p = z >> 3, h = z & 7;
  const float* in = ((p == 0) ? Wq : (p == 1) ? Wk : Wv) + (long)h * DD * AA;  // [D][A]
  __bf16* o = out + (long)(p * 1024 + h * 128) * DD;                           // [A][D]
  const int r0 = blockIdx.y * 64, c0 = blockIdx.x * 64;  // r over D, c over A
  for (int i = threadIdx.x; i < 4096; i += 256) {
    int r = i >> 6, c = i & 63;
    tile[r][c] = in[(long)(r0 + r) * AA + c0 + c];
  }
  __syncthreads();
  for (int i = threadIdx.x; i < 4096; i += 256) {
    int c = i >> 6, r = i & 63;
    o[(long)(c0 + c) * DD + r0 + r] = (__bf16)tile[r][c];
  }
}

__global__ void build_qkv_bias(const float* __restrict__ bq, const float* __restrict__ bk,
                               const float* __restrict__ bv, float* __restrict__ out) {
  int i = blockIdx.x * 256 + threadIdx.x;
  if (i < 3072) {
    const float* src = (i < 1024) ? bq : (i < 2048) ? bk : bv;
    out[i] = src[i & 1023];
  }
}

__global__ void conv_f32_bf16(const float* __restrict__ in, __bf16* __restrict__ out, int n4) {
  int i = blockIdx.x * 256 + threadIdx.x;
  if (i < n4) {
    float4 v = ((const float4*)in)[i];
    bf16x4 o = { (__bf16)v.x, (__bf16)v.y, (__bf16)v.z, (__bf16)v.w };
    ((bf16x4*)out)[i] = o;
  }
}

// ---------------- generic GEMM: C[M][N] = A[M][K](bf16) * Bt[N][K]^T + bias ----------------
template<bool RELU, bool RESID, bool OUTF, bool OUTB, bool WRVT>
__global__ __launch_bounds__(256) void gemm_bt(
    const __bf16* __restrict__ Ag, const __bf16* __restrict__ Bt,
    const float* __restrict__ bias, const float* __restrict__ resid,
    float* __restrict__ Cf, __bf16* __restrict__ Cb, __bf16* __restrict__ vTb,
    int M, int N, int K)
{
  __shared__ __bf16 As[128 * 32];
  __shared__ __bf16 Bs[128 * 32];
  const int t = threadIdx.x;
  const int w = t >> 6, l = t & 63;
  // XCD-aware swizzle (all grids are multiples of 8 blocks)
  const int gx = gridDim.x, nwg = gx * gridDim.y;
  int bid = blockIdx.y * gx + blockIdx.x;
  int swz = (bid & 7) * (nwg >> 3) + (bid >> 3);
  const int m0 = (swz / gx) * 128, n0 = (swz % gx) * 128;
  const int wr = w >> 1, wc = w & 1;
  const int lr = l & 15, lg = l >> 4;

  f32x4 acc[4][4] = {};

  const __bf16* gA = Ag + (long)(m0 + w * 32 + (l >> 2)) * K + (l & 3) * 8;
  const __bf16* gB = Bt + (long)(n0 + w * 32 + (l >> 2)) * K + (l & 3) * 8;
  __bf16* lA = &As[w * 1024];
  __bf16* lB = &Bs[w * 1024];

  for (int k0 = 0; k0 < K; k0 += 32) {
    gload_lds16(gA + k0, lA);
    gload_lds16(gA + (long)16 * K + k0, lA + 512);
    gload_lds16(gB + k0, lB);
    gload_lds16(gB + (long)16 * K + k0, lB + 512);
    __syncthreads();
    bf16x8 af[4], bfr[4];
#pragma unroll
    for (int mi = 0; mi < 4; mi++)
      af[mi] = *(const bf16x8*)&As[(wr * 64 + mi * 16 + lr) * 32 + lg * 8];
#pragma unroll
    for (int nj = 0; nj < 4; nj++)
      bfr[nj] = *(const bf16x8*)&Bs[(wc * 64 + nj * 16 + lr) * 32 + lg * 8];
#pragma unroll
    for (int mi = 0; mi < 4; mi++)
#pragma unroll
      for (int nj = 0; nj < 4; nj++)
        acc[mi][nj] = __builtin_amdgcn_mfma_f32_16x16x32_bf16(af[mi], bfr[nj], acc[mi][nj], 0, 0, 0);
    __syncthreads();
  }

#pragma unroll
  for (int mi = 0; mi < 4; mi++) {
    const int row0 = m0 + wr * 64 + mi * 16 + lg * 4;
#pragma unroll
    for (int nj = 0; nj < 4; nj++) {
      const int col = n0 + wc * 64 + nj * 16 + lr;
      const float bv = bias[col];
#pragma unroll
      for (int rg = 0; rg < 4; rg++) {
        const int row = row0 + rg;
        float v = acc[mi][nj][rg] + bv;
        if constexpr (RESID) v += resid[(long)row * N + col];
        if constexpr (RELU)  v = fmaxf(v, 0.f);
        if constexpr (OUTF)  Cf[(long)row * N + col] = v;
        if constexpr (OUTB)  Cb[(long)row * N + col] = (__bf16)v;
        if constexpr (WRVT) {
          if (col >= 2048) {  // V part -> also write V^T [b*8+h][a][s]
            int h = (col - 2048) >> 7, a = col & 127;
            int b = row >> 11, s = row & 2047;
            vTb[(((long)(b * 8 + h)) * 128 + a) * 2048 + s] = (__bf16)v;
          }
        }
      }
    }
  }
}

// ---------------- flash attention v2: swapped-operand 32x32 MFMA, in-register softmax ----
// grid (S/128, H, B); 4 waves x 32 q-rows; KVBLK=64 staged in LDS (XOR-swizzled, conflict-free).
// S^T = mfma(K,Q): lane owns q = lane&31; P stays in registers (cvt_pk + shfl_xor(32)).
__global__ __launch_bounds__(256) void attn_kernel(
    const __bf16* __restrict__ qkv,   // [8192][3072]  (q | k | v per head)
    const __bf16* __restrict__ vT,    // [B*H*128][2048]
    float* __restrict__ hsp)          // [H][8192][128] fp32 partials
{
  __shared__ __bf16 Ks[64 * 128];    // [kv][k], granule XOR (r&15)
  __shared__ __bf16 Vs[128 * 64];    // [a][kv], granule XOR (a&7)
  const int t = threadIdx.x, w = t >> 6, l = t & 63;
  const int q32 = l & 31, hi = l >> 5;
  const int h = blockIdx.y, b = blockIdx.z;
  const long rowbase = (long)b * SS + blockIdx.x * 128 + w * 32;
  const float C2 = (float)(0.08838834764831845 * 1.44269504088896340);  // inv_sqrt(128)*log2(e)

  // Q fragments: B-operand, col n = q32, k-contig 8 at hi*8 (+16 per ks)
  bf16x8 qf[8];
  {
    const __bf16* qrow = qkv + (rowbase + q32) * 3072 + h * 128;
#pragma unroll
    for (int ks = 0; ks < 8; ks++) qf[ks] = *(const bf16x8*)(qrow + ks * 16 + hi * 8);
  }

  float mrun = -1e30f, lrun = 0.f;
  f32x16 O[4] = {};

  const __bf16* kbase = qkv + (long)b * SS * 3072 + 1024 + h * 128;
  const __bf16* vbase = vT + ((long)(b * 8 + h) * 128) * 2048;

  for (int kt = 0; kt < 32; kt++) {
    const int kv0 = kt * 64;
    // ---- stage K [64][128] and V^T [128][64] (source pre-swizzled, linear LDS dest)
#pragma unroll
    for (int i = 0; i < 4; i++) {
      const int cb = (i * 4 + w) * 64;                  // chunk base for this wave-issue
      const int rK = (cb + l) >> 4, cK = l & 15;        // K row / 16B-chunk
      gload_lds16(kbase + (long)(kv0 + rK) * 3072 + ((cK ^ (rK & 15)) << 3),
                  (char*)Ks + cb * 16);
      const int aV = (cb >> 3) + (l >> 3), cV = l & 7;  // V row (a) / chunk
      gload_lds16(vbase + (long)aV * 2048 + kv0 + ((cV ^ (aV & 7)) << 3),
                  (char*)Vs + cb * 16);
    }
    __syncthreads();

    // ---- S^T = K * Q^T : lane holds q=q32, kv rows crow(reg,hi) per 32-subtile
    f32x16 st[2] = {};
#pragma unroll
    for (int s2 = 0; s2 < 2; s2++) {
      const int r = s2 * 32 + q32;
#pragma unroll
      for (int ks = 0; ks < 8; ks++) {
        const int g = (2 * ks + hi) ^ (r & 15);
        bf16x8 kf = *(const bf16x8*)((const char*)Ks + r * 256 + (g << 4));
        st[s2] = __builtin_amdgcn_mfma_f32_32x32x16_bf16(kf, qf[ks], st[s2], 0, 0, 0);
      }
    }

    // ---- online softmax, per-lane q-row (raw scores; scale folded into exp2)
    float pmax = st[0][0];
#pragma unroll
    for (int s2 = 0; s2 < 2; s2++)
#pragma unroll
      for (int rg = 0; rg < 16; rg++) pmax = fmaxf(pmax, st[s2][rg]);
    pmax = fmaxf(pmax, __shfl_xor(pmax, 32));

    if (!__all(pmax - mrun <= 64.f)) {   // defer-max: raw THR 64 -> P <= 2^8.2
      const float mnew = fmaxf(mrun, pmax);
      const float sscl = exp2f((mrun - mnew) * C2);
      lrun *= sscl;
      mrun = mnew;
      float ssb[16];
#pragma unroll
      for (int rg = 0; rg < 16; rg++)
        ssb[rg] = __shfl(sscl, (l & 32) + ((rg & 3) + 8 * (rg >> 2) + 4 * hi));
#pragma unroll
      for (int aj = 0; aj < 4; aj++)
#pragma unroll
        for (int rg = 0; rg < 16; rg++) O[aj][rg] *= ssb[rg];
    }

    float rsum = 0.f;
#pragma unroll
    for (int s2 = 0; s2 < 2; s2++)
#pragma unroll
      for (int rg = 0; rg < 16; rg++) {
        const float p = exp2f((st[s2][rg] - mrun) * C2);
        st[s2][rg] = p;
        rsum += p;
      }
    rsum += __shfl_xor(rsum, 32);
    lrun += rsum;

    // ---- PV: build A-frag (P[q][kv 16c..16c+15]) in-register, B-frag = V^T from LDS
#pragma unroll
    for (int c = 0; c < 4; c++) {
      const int sA = (2 * c) >> 2, tA = (2 * c) & 3;
      const int sB = (2 * c + 1) >> 2, tB = (2 * c + 1) & 3;
      uint32_t W01a, W23a, W01b, W23b;
      asm("v_cvt_pk_bf16_f32 %0, %1, %2" : "=v"(W01a) : "v"(st[sA][4*tA+0]), "v"(st[sA][4*tA+1]));
      asm("v_cvt_pk_bf16_f32 %0, %1, %2" : "=v"(W23a) : "v"(st[sA][4*tA+2]), "v"(st[sA][4*tA+3]));
      asm("v_cvt_pk_bf16_f32 %0, %1, %2" : "=v"(W01b) : "v"(st[sB][4*tB+0]), "v"(st[sB][4*tB+1]));
      asm("v_cvt_pk_bf16_f32 %0, %1, %2" : "=v"(W23b) : "v"(st[sB][4*tB+2]), "v"(st[sB][4*tB+3]));
      const uint32_t X01 = __shfl_xor(hi ? W01a : W01b, 32);
      const uint32_t X23 = __shfl_xor(hi ? W23a : W23b, 32);
      union { uint32_t u[4]; bf16x8 v; } pa;
      pa.u[0] = hi ? X01 : W01a;   // kv 8j+0,1   (j = 2c+hi)
      pa.u[1] = hi ? X23 : W23a;   // kv 8j+2,3
      pa.u[2] = hi ? W01b : X01;   // kv 8j+4,5
      pa.u[3] = hi ? W23b : X23;   // kv 8j+6,7
#pragma unroll
      for (int aj = 0; aj < 4; aj++) {
        const int a = aj * 32 + q32;
        const int gv = (2 * c + hi) ^ (a & 7);
        bf16x8 vf = *(const bf16x8*)((const char*)Vs + a * 128 + (gv << 4));
        O[aj] = __builtin_amdgcn_mfma_f32_32x32x16_bf16(pa.v, vf, O[aj], 0, 0, 0);
      }
    }
    __syncthreads();  // all Ks/Vs reads done before next-tile overwrite
  }

  // ---- normalize + store (O rows = crow(reg,hi), cols = aj*32+q32)
  const float invl = 1.f / lrun;
  float invb[16];
#pragma unroll
  for (int rg = 0; rg < 16; rg++)
    invb[rg] = __shfl(invl, (l & 32) + ((rg & 3) + 8 * (rg >> 2) + 4 * hi));
  float* ho = hsp + ((long)h * MM + rowbase) * AA;
#pragma unroll
  for (int aj = 0; aj < 4; aj++)
#pragma unroll
    for (int rg = 0; rg < 16; rg++) {
      const int qr = (rg & 3) + 8 * (rg >> 2) + 4 * hi;
      ho[(long)qr * AA + aj * 32 + q32] = O[aj][rg] * invb[rg];
    }
}

// ---------------- sum 8 per-head partials -> bf16 ----------------
__global__ __launch_bounds__(256) void reduce_heads(const float* __restrict__ hsp,
                                                    __bf16* __restrict__ out) {
  const long i = (long)blockIdx.x * 256 + threadIdx.x;  // over MM*AA/4 float4s
  const float4* p = (const float4*)hsp;
  float4 s = p[i];
#pragma unroll
  for (int h = 1; h < 8; h++) {
    float4 v = p[i + (long)h * (MM * AA / 4)];
    s.x += v.x; s.y += v.y; s.z += v.z; s.w += v.w;
  }
  bf16x4 o = { (__bf16)s.x, (__bf16)s.y, (__bf16)s.z, (__bf16)s.w };
  ((bf16x4*)out)[i] = o;
}

// ---------------- LayerNorm over D=1024 (one block per row) ----------------
template<bool WB>
__global__ __launch_bounds__(256) void ln_kernel(
    const float* __restrict__ in, const float* __restrict__ g, const float* __restrict__ be,
    float* __restrict__ outf, __bf16* __restrict__ outb)
{
  const int row = blockIdx.x, t = threadIdx.x;
  const float4 xv = *(const float4*)(in + (long)row * DD + t * 4);
  float s = xv.x + xv.y + xv.z + xv.w;
  float s2 = xv.x * xv.x + xv.y * xv.y + xv.z * xv.z + xv.w * xv.w;
#pragma unroll
  for (int off = 32; off >= 1; off >>= 1) {
    s += __shfl_down(s, off);
    s2 += __shfl_down(s2, off);
  }
  __shared__ float sm[4], sm2[4];
  __shared__ float mu_s, rs_s;
  const int wid = t >> 6;
  if ((t & 63) == 0) { sm[wid] = s; sm2[wid] = s2; }
  __syncthreads();
  if (t == 0) {
    float S = sm[0] + sm[1] + sm[2] + sm[3];
    float S2 = sm2[0] + sm2[1] + sm2[2] + sm2[3];
    float mu = S * (1.f / 1024.f);
    float var = S2 * (1.f / 1024.f) - mu * mu;
    mu_s = mu;
    rs_s = rsqrtf(var + EPSV);
  }
  __syncthreads();
  const float mu = mu_s, rs = rs_s;
  const float4 gv = *(const float4*)(g + t * 4);
  const float4 bv = *(const float4*)(be + t * 4);
  float o0 = (xv.x - mu) * rs * gv.x + bv.x;
  float o1 = (xv.y - mu) * rs * gv.y + bv.y;
  float o2 = (xv.z - mu) * rs * gv.z + bv.z;
  float o3 = (xv.w - mu) * rs * gv.w + bv.w;
  float4 ov = { o0, o1, o2, o3 };
  *(float4*)(outf + (long)row * DD + t * 4) = ov;
  if constexpr (WB) {
    bf16x4 ob = { (__bf16)o0, (__bf16)o1, (__bf16)o2, (__bf16)o3 };
    *(bf16x4*)(outb + (long)row * DD + t * 4) = ob;
  }
}

// ---------------- launch ----------------
extern "C" void kernel_launch(void* const* d_in, const int* in_sizes, int n_in,
                              void* d_out, int out_size, void* d_ws, size_t ws_size,
                              hipStream_t stream) {
  const float* x    = (const float*)d_in[0];
  const float* Wq   = (const float*)d_in[1];
  const float* bq   = (const float*)d_in[2];
  const float* Wk   = (const float*)d_in[3];
  const float* bk   = (const float*)d_in[4];
  const float* Wv   = (const float*)d_in[5];
  const float* bv   = (const float*)d_in[6];
  const float* Wo   = (const float*)d_in[7];
  const float* bo   = (const float*)d_in[8];
  const float* g1   = (const float*)d_in[9];
  const float* be1  = (const float*)d_in[10];
  const float* g2   = (const float*)d_in[11];
  const float* be2  = (const float*)d_in[12];
  const float* W1   = (const float*)d_in[13];
  const float* bf1  = (const float*)d_in[14];
  const float* W2   = (const float*)d_in[15];
  const float* bf2  = (const float*)d_in[16];

  const size_t MB = 1ull << 20;
  char* ws = (char*)d_ws;
  __bf16* WqkvT    = (__bf16*)(ws + 0);         // 6 MB   [3072][1024]
  float*  qkv_bias = (float*) (ws + 6 * MB);    // 12 KB
  __bf16* WoT      = (__bf16*)(ws + 7 * MB);    // 256 KB [1024][128]
  __bf16* W1T      = (__bf16*)(ws + 8 * MB);    // 8 MB   [4096][1024]
  __bf16* W2T      = (__bf16*)(ws + 16 * MB);   // 8 MB   [1024][4096]
  __bf16* xb       = (__bf16*)(ws + 24 * MB);   // 16 MB  [8192][1024]
  __bf16* qkvb     = (__bf16*)(ws + 40 * MB);   // 48 MB  [8192][3072]
  __bf16* vTb      = (__bf16*)(ws + 88 * MB);   // 16 MB  [4096][2048]
  float*  hsp      = (float*) (ws + 104 * MB);  // 32 MB  [8][8192][128] fp32 partials
  __bf16* hs_b     = (__bf16*)(ws + 136 * MB);  // 2 MB
  float*  tt       = (float*) (ws + 104 * MB);  // 32 MB  (overlays hsp; hsp dead before out-proj)
  float*  yy       = (float*) (ws + 140 * MB);  // 32 MB  (post-LN1 fp32)
  __bf16* yb       = (__bf16*)(ws + 172 * MB);  // 16 MB
  __bf16* hb       = (__bf16*)(ws + 24 * MB);   // 64 MB, overlays xb/qkvb (dead by FFN1)

  // weight prep
  transpose_qkv<<<dim3(2, 16, 24), 256, 0, stream>>>(Wq, Wk, Wv, WqkvT);
  build_qkv_bias<<<12, 256, 0, stream>>>(bq, bk, bv, qkv_bias);
  transpose_conv<<<dim3(16, 2), 256, 0, stream>>>(Wo, WoT, 128, 1024);
  transpose_conv<<<dim3(64, 16), 256, 0, stream>>>(W1, W1T, 1024, 4096);
  transpose_conv<<<dim3(16, 64), 256, 0, stream>>>(W2, W2T, 4096, 1024);
  conv_f32_bf16<<<8192, 256, 0, stream>>>(x, xb, MM * DD / 4);

  // QKV projection (writes q,k,v bf16 + V^T)
  gemm_bt<false, false, false, true, true><<<dim3(24, 64), 256, 0, stream>>>(
      xb, WqkvT, qkv_bias, nullptr, nullptr, qkvb, vTb, MM, 3072, 1024);

  // attention -> per-head partials, then reduce
  attn_kernel<<<dim3(16, 8, 4), 256, 0, stream>>>(qkvb, vTb, hsp);
  reduce_heads<<<MM * AA / 4 / 256, 256, 0, stream>>>(hsp, hs_b);

  // out projection + residual(x)
  gemm_bt<false, true, true, false, false><<<dim3(8, 64), 256, 0, stream>>>(
      hs_b, WoT, bo, x, tt, nullptr, nullptr, MM, 1024, 128);
  ln_kernel<true><<<MM, 256, 0, stream>>>(tt, g1, be1, yy, yb);

  // FFN
  gemm_bt<true, false, false, true, false><<<dim3(32, 64), 256, 0, stream>>>(
      yb, W1T, bf1, nullptr, nullptr, hb, nullptr, MM, FF, 1024);
  gemm_bt<false, true, true, false, false><<<dim3(8, 64), 256, 0, stream>>>(
      hb, W2T, bf2, yy, tt, nullptr, nullptr, MM, DD, FF);
  ln_kernel<false><<<MM, 256, 0, stream>>>(tt, g2, be2, (float*)d_out, nullptr);
}

// Round 5
// 610.022 us; speedup vs baseline: 1.0714x; 1.0714x over previous
//
#include <hip/hip_runtime.h>
#include <hip/hip_bf16.h>
#include <stdint.h>

// Problem constants
#define DD 1024
#define AA 128
#define HH 8
#define FF 4096
#define BB 4
#define SS 2048
#define MM (BB*SS)      // 8192 tokens
#define EPSV 1e-5f

typedef __bf16 bf16x8 __attribute__((ext_vector_type(8)));
typedef __bf16 bf16x4 __attribute__((ext_vector_type(4)));
typedef float  f32x4  __attribute__((ext_vector_type(4)));
typedef float  f32x16 __attribute__((ext_vector_type(16)));

// ---------------- async global->LDS (16B per lane) ----------------
__device__ __forceinline__ void gload_lds16(const void* g, void* l) {
  __builtin_amdgcn_global_load_lds(
      (const __attribute__((address_space(1))) uint32_t*)(uintptr_t)g,
      (__attribute__((address_space(3))) uint32_t*)(uintptr_t)l, 16, 0, 0);
}

// ---------------- transpose + f32->bf16 convert: out[c][r] = in[r][c] ----------------
__global__ __launch_bounds__(256) void transpose_conv(const float* __restrict__ in,
                                                      __bf16* __restrict__ out,
                                                      int rows, int cols) {
  __shared__ float tile[64][65];
  const int r0 = blockIdx.y * 64, c0 = blockIdx.x * 64;
  for (int i = threadIdx.x; i < 4096; i += 256) {
    int r = i >> 6, c = i & 63;
    tile[r][c] = in[(long)(r0 + r) * cols + c0 + c];
  }
  __syncthreads();
  for (int i = threadIdx.x; i < 4096; i += 256) {
    int c = i >> 6, r = i & 63;
    out[(long)(c0 + c) * rows + r0 + r] = (__bf16)tile[r][c];
  }
}

// QKV weights: Wq/Wk/Wv are [H][D][A]; build WqkvT [3072][1024] (row n = p*1024+h*128+a, col d)
__global__ __launch_bounds__(256) void transpose_qkv(const float* __restrict__ Wq,
                                                     const float* __restrict__ Wk,
                                                     const float* __restrict__ Wv,
                                                     __bf16* __restrict__ out) {
  __shared__ float tile[64][65];
  const int z = blockIdx.z;
  const int p = z >> 3, h = z & 7;
  const float* in = ((p == 0) ? Wq : (p == 1) ? Wk : Wv) + (long)h * DD * AA;  // [D][A]
  __bf16* o = out + (long)(p * 1024 + h * 128) * DD;                           // [A][D]
  const int r0 = blockIdx.y * 64, c0 = blockIdx.x * 64;  // r over D, c over A
  for (int i = threadIdx.x; i < 4096; i += 256) {
    int r = i >> 6, c = i & 63;
    tile[r][c] = in[(long)(r0 + r) * AA + c0 + c];
  }
  __syncthreads();
  for (int i = threadIdx.x; i < 4096; i += 256) {
    int c = i >> 6, r = i & 63;
    o[(long)(c0 + c) * DD + r0 + r] = (__bf16)tile[r][c];
  }
}

// V columns of qkvb -> vTb [b*8+h][a][s], LDS-tiled, coalesced both sides
__global__ __launch_bounds__(256) void transpose_v(const __bf16* __restrict__ qkvb,
                                                   __bf16* __restrict__ vTb) {
  __shared__ float tile[64][65];
  const int s0 = blockIdx.x * 64, a0 = blockIdx.y * 64;
  const int bh = blockIdx.z, b = bh >> 3, h = bh & 7;
  const __bf16* src = qkvb + ((long)b * SS) * 3072 + 2048 + h * 128;
  for (int i = threadIdx.x; i < 4096; i += 256) {
    int r = i >> 6, c = i & 63;   // r: s, c: a
    tile[r][c] = (float)src[(long)(s0 + r) * 3072 + a0 + c];
  }
  __syncthreads();
  __bf16* dst = vTb + ((long)bh * 128) * 2048;
  for (int i = threadIdx.x; i < 4096; i += 256) {
    int c = i >> 6, r = i & 63;   // consecutive threads -> consecutive s
    dst[(long)(a0 + c) * 2048 + s0 + r] = (__bf16)tile[r][c];
  }
}

__global__ void build_qkv_bias(const float* __restrict__ bq, const float* __restrict__ bk,
                               const float* __restrict__ bv, float* __restrict__ out) {
  int i = blockIdx.x * 256 + threadIdx.x;
  if (i < 3072) {
    const float* src = (i < 1024) ? bq : (i < 2048) ? bk : bv;
    out[i] = src[i & 1023];
  }
}

__global__ void conv_f32_bf16(const float* __restrict__ in, __bf16* __restrict__ out, int n4) {
  int i = blockIdx.x * 256 + threadIdx.x;
  if (i < n4) {
    float4 v = ((const float4*)in)[i];
    bf16x4 o = { (__bf16)v.x, (__bf16)v.y, (__bf16)v.z, (__bf16)v.w };
    ((bf16x4*)out)[i] = o;
  }
}

// ---------------- generic GEMM: C[M][N] = A[M][K](bf16) * Bt[N][K]^T + bias ----------------
template<bool RELU, bool RESID, bool OUTF, bool OUTB>
__global__ __launch_bounds__(256) void gemm_bt(
    const __bf16* __restrict__ Ag, const __bf16* __restrict__ Bt,
    const float* __restrict__ bias, const float* __restrict__ resid,
    float* __restrict__ Cf, __bf16* __restrict__ Cb,
    int M, int N, int K)
{
  __shared__ __bf16 As[128 * 32];
  __shared__ __bf16 Bs[128 * 32];
  const int t = threadIdx.x;
  const int w = t >> 6, l = t & 63;
  // XCD-aware swizzle (all grids are multiples of 8 blocks)
  const int gx = gridDim.x, nwg = gx * gridDim.y;
  int bid = blockIdx.y * gx + blockIdx.x;
  int swz = (bid & 7) * (nwg >> 3) + (bid >> 3);
  const int m0 = (swz / gx) * 128, n0 = (swz % gx) * 128;
  const int wr = w >> 1, wc = w & 1;
  const int lr = l & 15, lg = l >> 4;

  f32x4 acc[4][4] = {};

  const __bf16* gA = Ag + (long)(m0 + w * 32 + (l >> 2)) * K + (l & 3) * 8;
  const __bf16* gB = Bt + (long)(n0 + w * 32 + (l >> 2)) * K + (l & 3) * 8;
  __bf16* lA = &As[w * 1024];
  __bf16* lB = &Bs[w * 1024];

  for (int k0 = 0; k0 < K; k0 += 32) {
    gload_lds16(gA + k0, lA);
    gload_lds16(gA + (long)16 * K + k0, lA + 512);
    gload_lds16(gB + k0, lB);
    gload_lds16(gB + (long)16 * K + k0, lB + 512);
    __syncthreads();
    bf16x8 af[4], bfr[4];
#pragma unroll
    for (int mi = 0; mi < 4; mi++)
      af[mi] = *(const bf16x8*)&As[(wr * 64 + mi * 16 + lr) * 32 + lg * 8];
#pragma unroll
    for (int nj = 0; nj < 4; nj++)
      bfr[nj] = *(const bf16x8*)&Bs[(wc * 64 + nj * 16 + lr) * 32 + lg * 8];
#pragma unroll
    for (int mi = 0; mi < 4; mi++)
#pragma unroll
      for (int nj = 0; nj < 4; nj++)
        acc[mi][nj] = __builtin_amdgcn_mfma_f32_16x16x32_bf16(af[mi], bfr[nj], acc[mi][nj], 0, 0, 0);
    __syncthreads();
  }

#pragma unroll
  for (int mi = 0; mi < 4; mi++) {
    const int row0 = m0 + wr * 64 + mi * 16 + lg * 4;
#pragma unroll
    for (int nj = 0; nj < 4; nj++) {
      const int col = n0 + wc * 64 + nj * 16 + lr;
      const float bv = bias[col];
#pragma unroll
      for (int rg = 0; rg < 4; rg++) {
        const int row = row0 + rg;
        float v = acc[mi][nj][rg] + bv;
        if constexpr (RESID) v += resid[(long)row * N + col];
        if constexpr (RELU)  v = fmaxf(v, 0.f);
        if constexpr (OUTF)  Cf[(long)row * N + col] = v;
        if constexpr (OUTB)  Cb[(long)row * N + col] = (__bf16)v;
      }
    }
  }
}

// ---------------- flash attention: swapped-operand 32x32 MFMA, in-register softmax ----
// grid (S/128, H, B); 4 waves x 32 q-rows; KVBLK=64, double-buffered LDS (XOR-swizzled).
// 2-phase pipeline: STAGE(next) issued before compute(cur); one __syncthreads per tile.
__global__ __launch_bounds__(256) void attn_kernel(
    const __bf16* __restrict__ qkv,   // [8192][3072]  (q | k | v per head)
    const __bf16* __restrict__ vT,    // [B*H*128][2048]
    float* __restrict__ hsp)          // [H][8192][128] fp32 partials
{
  __shared__ __bf16 Ks[2][64 * 128];    // [kv][k], granule XOR (r&15)
  __shared__ __bf16 Vs[2][128 * 64];    // [a][kv], granule XOR (a&7)
  const int t = threadIdx.x, w = t >> 6, l = t & 63;
  const int q32 = l & 31, hi = l >> 5;
  const int h = blockIdx.y, b = blockIdx.z;
  const long rowbase = (long)b * SS + blockIdx.x * 128 + w * 32;
  const float C2 = (float)(0.08838834764831845 * 1.44269504088896340);  // inv_sqrt(128)*log2(e)

  const __bf16* kbase = qkv + (long)b * SS * 3072 + 1024 + h * 128;
  const __bf16* vbase = vT + ((long)(b * 8 + h) * 128) * 2048;

  // Q fragments: B-operand, col n = q32, k-contig 8 at hi*8 (+16 per ks)
  bf16x8 qf[8];
  {
    const __bf16* qrow = qkv + (rowbase + q32) * 3072 + h * 128;
#pragma unroll
    for (int ks = 0; ks < 8; ks++) qf[ks] = *(const bf16x8*)(qrow + ks * 16 + hi * 8);
  }

  float mrun = -1e30f, lrun = 0.f;
  f32x16 O[4] = {};

#define STAGE(BUF, KV0)                                                              \
  {                                                                                  \
    _Pragma("unroll")                                                                \
    for (int i = 0; i < 4; i++) {                                                    \
      const int cb = (i * 4 + w) * 64;                                               \
      const int rK = (cb + l) >> 4, cK = l & 15;                                     \
      gload_lds16(kbase + (long)((KV0) + rK) * 3072 + ((cK ^ (rK & 15)) << 3),       \
                  (char*)Ks[BUF] + cb * 16);                                         \
      const int aV = (cb >> 3) + (l >> 3), cV = l & 7;                               \
      gload_lds16(vbase + (long)aV * 2048 + (KV0) + ((cV ^ (aV & 7)) << 3),          \
                  (char*)Vs[BUF] + cb * 16);                                         \
    }                                                                                \
  }

  STAGE(0, 0);
  __syncthreads();            // drains vmcnt(0): buf0 ready
  int cur = 0;

  for (int kt = 0; kt < 32; kt++) {
    // prefetch next tile into the other buffer; loads fly during compute below
    if (kt < 31) STAGE(cur ^ 1, (kt + 1) * 64);

    // ---- S^T = K * Q^T : lane holds q=q32, kv rows crow(reg,hi) per 32-subtile
    f32x16 st[2] = {};
    __builtin_amdgcn_s_setprio(1);
#pragma unroll
    for (int s2 = 0; s2 < 2; s2++) {
      const int r = s2 * 32 + q32;
#pragma unroll
      for (int ks = 0; ks < 8; ks++) {
        const int g = (2 * ks + hi) ^ (r & 15);
        bf16x8 kf = *(const bf16x8*)((const char*)Ks[cur] + r * 256 + (g << 4));
        st[s2] = __builtin_amdgcn_mfma_f32_32x32x16_bf16(kf, qf[ks], st[s2], 0, 0, 0);
      }
    }
    __builtin_amdgcn_s_setprio(0);

    // ---- online softmax, per-lane q-row (raw scores; scale folded into exp2)
    float pmax = st[0][0];
#pragma unroll
    for (int s2 = 0; s2 < 2; s2++)
#pragma unroll
      for (int rg = 0; rg < 16; rg++) pmax = fmaxf(pmax, st[s2][rg]);
    pmax = fmaxf(pmax, __shfl_xor(pmax, 32));

    if (!__all(pmax - mrun <= 64.f)) {   // defer-max: raw THR 64 -> P <= 2^8.2
      const float mnew = fmaxf(mrun, pmax);
      const float sscl = exp2f((mrun - mnew) * C2);
      lrun *= sscl;
      mrun = mnew;
      float ssb[16];
#pragma unroll
      for (int rg = 0; rg < 16; rg++)
        ssb[rg] = __shfl(sscl, (l & 32) + ((rg & 3) + 8 * (rg >> 2) + 4 * hi));
#pragma unroll
      for (int aj = 0; aj < 4; aj++)
#pragma unroll
        for (int rg = 0; rg < 16; rg++) O[aj][rg] *= ssb[rg];
    }

    float rsum = 0.f;
#pragma unroll
    for (int s2 = 0; s2 < 2; s2++)
#pragma unroll
      for (int rg = 0; rg < 16; rg++) {
        const float p = exp2f((st[s2][rg] - mrun) * C2);
        st[s2][rg] = p;
        rsum += p;
      }
    rsum += __shfl_xor(rsum, 32);
    lrun += rsum;

    // ---- PV: build A-frag (P[q][kv 16c..16c+15]) in-register, B-frag = V^T from LDS
    __builtin_amdgcn_s_setprio(1);
#pragma unroll
    for (int c = 0; c < 4; c++) {
      const int sA = (2 * c) >> 2, tA = (2 * c) & 3;
      const int sB = (2 * c + 1) >> 2, tB = (2 * c + 1) & 3;
      uint32_t W01a, W23a, W01b, W23b;
      asm("v_cvt_pk_bf16_f32 %0, %1, %2" : "=v"(W01a) : "v"(st[sA][4*tA+0]), "v"(st[sA][4*tA+1]));
      asm("v_cvt_pk_bf16_f32 %0, %1, %2" : "=v"(W23a) : "v"(st[sA][4*tA+2]), "v"(st[sA][4*tA+3]));
      asm("v_cvt_pk_bf16_f32 %0, %1, %2" : "=v"(W01b) : "v"(st[sB][4*tB+0]), "v"(st[sB][4*tB+1]));
      asm("v_cvt_pk_bf16_f32 %0, %1, %2" : "=v"(W23b) : "v"(st[sB][4*tB+2]), "v"(st[sB][4*tB+3]));
      const uint32_t X01 = __shfl_xor(hi ? W01a : W01b, 32);
      const uint32_t X23 = __shfl_xor(hi ? W23a : W23b, 32);
      union { uint32_t u[4]; bf16x8 v; } pa;
      pa.u[0] = hi ? X01 : W01a;   // kv 8j+0,1   (j = 2c+hi)
      pa.u[1] = hi ? X23 : W23a;   // kv 8j+2,3
      pa.u[2] = hi ? W01b : X01;   // kv 8j+4,5
      pa.u[3] = hi ? W23b : X23;   // kv 8j+6,7
#pragma unroll
      for (int aj = 0; aj < 4; aj++) {
        const int a = aj * 32 + q32;
        const int gv = (2 * c + hi) ^ (a & 7);
        bf16x8 vf = *(const bf16x8*)((const char*)Vs[cur] + a * 128 + (gv << 4));
        O[aj] = __builtin_amdgcn_mfma_f32_32x32x16_bf16(pa.v, vf, O[aj], 0, 0, 0);
      }
    }
    __builtin_amdgcn_s_setprio(0);

    __syncthreads();  // drains vmcnt(0): next buf staged; all Ks/Vs[cur] reads done
    cur ^= 1;
  }
#undef STAGE

  // ---- normalize + store (O rows = crow(reg,hi), cols = aj*32+q32)
  const float invl = 1.f / lrun;
  float invb[16];
#pragma unroll
  for (int rg = 0; rg < 16; rg++)
    invb[rg] = __shfl(invl, (l & 32) + ((rg & 3) + 8 * (rg >> 2) + 4 * hi));
  float* ho = hsp + ((long)h * MM + rowbase) * AA;
#pragma unroll
  for (int aj = 0; aj < 4; aj++)
#pragma unroll
    for (int rg = 0; rg < 16; rg++) {
      const int qr = (rg & 3) + 8 * (rg >> 2) + 4 * hi;
      ho[(long)qr * AA + aj * 32 + q32] = O[aj][rg] * invb[rg];
    }
}

// ---------------- sum 8 per-head partials -> bf16 ----------------
__global__ __launch_bounds__(256) void reduce_heads(const float* __restrict__ hsp,
                                                    __bf16* __restrict__ out) {
  const long i = (long)blockIdx.x * 256 + threadIdx.x;  // over MM*AA/4 float4s
  const float4* p = (const float4*)hsp;
  float4 s = p[i];
#pragma unroll
  for (int h = 1; h < 8; h++) {
    float4 v = p[i + (long)h * (MM * AA / 4)];
    s.x += v.x; s.y += v.y; s.z += v.z; s.w += v.w;
  }
  bf16x4 o = { (__bf16)s.x, (__bf16)s.y, (__bf16)s.z, (__bf16)s.w };
  ((bf16x4*)out)[i] = o;
}

// ---------------- LayerNorm over D=1024 (one block per row) ----------------
template<bool WB>
__global__ __launch_bounds__(256) void ln_kernel(
    const float* __restrict__ in, const float* __restrict__ g, const float* __restrict__ be,
    float* __restrict__ outf, __bf16* __restrict__ outb)
{
  const int row = blockIdx.x, t = threadIdx.x;
  const float4 xv = *(const float4*)(in + (long)row * DD + t * 4);
  float s = xv.x + xv.y + xv.z + xv.w;
  float s2 = xv.x * xv.x + xv.y * xv.y + xv.z * xv.z + xv.w * xv.w;
#pragma unroll
  for (int off = 32; off >= 1; off >>= 1) {
    s += __shfl_down(s, off);
    s2 += __shfl_down(s2, off);
  }
  __shared__ float sm[4], sm2[4];
  __shared__ float mu_s, rs_s;
  const int wid = t >> 6;
  if ((t & 63) == 0) { sm[wid] = s; sm2[wid] = s2; }
  __syncthreads();
  if (t == 0) {
    float S = sm[0] + sm[1] + sm[2] + sm[3];
    float S2 = sm2[0] + sm2[1] + sm2[2] + sm2[3];
    float mu = S * (1.f / 1024.f);
    float var = S2 * (1.f / 1024.f) - mu * mu;
    mu_s = mu;
    rs_s = rsqrtf(var + EPSV);
  }
  __syncthreads();
  const float mu = mu_s, rs = rs_s;
  const float4 gv = *(const float4*)(g + t * 4);
  const float4 bv = *(const float4*)(be + t * 4);
  float o0 = (xv.x - mu) * rs * gv.x + bv.x;
  float o1 = (xv.y - mu) * rs * gv.y + bv.y;
  float o2 = (xv.z - mu) * rs * gv.z + bv.z;
  float o3 = (xv.w - mu) * rs * gv.w + bv.w;
  float4 ov = { o0, o1, o2, o3 };
  *(float4*)(outf + (long)row * DD + t * 4) = ov;
  if constexpr (WB) {
    bf16x4 ob = { (__bf16)o0, (__bf16)o1, (__bf16)o2, (__bf16)o3 };
    *(bf16x4*)(outb + (long)row * DD + t * 4) = ob;
  }
}

// ---------------- launch ----------------
extern "C" void kernel_launch(void* const* d_in, const int* in_sizes, int n_in,
                              void* d_out, int out_size, void* d_ws, size_t ws_size,
                              hipStream_t stream) {
  const float* x    = (const float*)d_in[0];
  const float* Wq   = (const float*)d_in[1];
  const float* bq   = (const float*)d_in[2];
  const float* Wk   = (const float*)d_in[3];
  const float* bk   = (const float*)d_in[4];
  const float* Wv   = (const float*)d_in[5];
  const float* bv   = (const float*)d_in[6];
  const float* Wo   = (const float*)d_in[7];
  const float* bo   = (const float*)d_in[8];
  const float* g1   = (const float*)d_in[9];
  const float* be1  = (const float*)d_in[10];
  const float* g2   = (const float*)d_in[11];
  const float* be2  = (const float*)d_in[12];
  const float* W1   = (const float*)d_in[13];
  const float* bf1  = (const float*)d_in[14];
  const float* W2   = (const float*)d_in[15];
  const float* bf2  = (const float*)d_in[16];

  const size_t MB = 1ull << 20;
  char* ws = (char*)d_ws;
  __bf16* WqkvT    = (__bf16*)(ws + 0);         // 6 MB   [3072][1024]
  float*  qkv_bias = (float*) (ws + 6 * MB);    // 12 KB
  __bf16* WoT      = (__bf16*)(ws + 7 * MB);    // 256 KB [1024][128]
  __bf16* W1T      = (__bf16*)(ws + 8 * MB);    // 8 MB   [4096][1024]
  __bf16* W2T      = (__bf16*)(ws + 16 * MB);   // 8 MB   [1024][4096]
  __bf16* xb       = (__bf16*)(ws + 24 * MB);   // 16 MB  [8192][1024]
  __bf16* qkvb     = (__bf16*)(ws + 40 * MB);   // 48 MB  [8192][3072]
  __bf16* vTb      = (__bf16*)(ws + 88 * MB);   // 16 MB  [4096][2048]
  float*  hsp      = (float*) (ws + 104 * MB);  // 32 MB  [8][8192][128] fp32 partials
  __bf16* hs_b     = (__bf16*)(ws + 136 * MB);  // 2 MB
  float*  tt       = (float*) (ws + 104 * MB);  // 32 MB  (overlays hsp; hsp dead before out-proj)
  float*  yy       = (float*) (ws + 140 * MB);  // 32 MB  (post-LN1 fp32)
  __bf16* yb       = (__bf16*)(ws + 172 * MB);  // 16 MB
  __bf16* hb       = (__bf16*)(ws + 24 * MB);   // 64 MB, overlays xb/qkvb (dead by FFN1)

  // weight prep
  transpose_qkv<<<dim3(2, 16, 24), 256, 0, stream>>>(Wq, Wk, Wv, WqkvT);
  build_qkv_bias<<<12, 256, 0, stream>>>(bq, bk, bv, qkv_bias);
  transpose_conv<<<dim3(16, 2), 256, 0, stream>>>(Wo, WoT, 128, 1024);
  transpose_conv<<<dim3(64, 16), 256, 0, stream>>>(W1, W1T, 1024, 4096);
  transpose_conv<<<dim3(16, 64), 256, 0, stream>>>(W2, W2T, 4096, 1024);
  conv_f32_bf16<<<8192, 256, 0, stream>>>(x, xb, MM * DD / 4);

  // QKV projection (q,k,v bf16), then V^T via coalesced transpose
  gemm_bt<false, false, false, true><<<dim3(24, 64), 256, 0, stream>>>(
      xb, WqkvT, qkv_bias, nullptr, nullptr, qkvb, MM, 3072, 1024);
  transpose_v<<<dim3(32, 2, 32), 256, 0, stream>>>(qkvb, vTb);

  // attention -> per-head partials, then reduce
  attn_kernel<<<dim3(16, 8, 4), 256, 0, stream>>>(qkvb, vTb, hsp);
  reduce_heads<<<MM * AA / 4 / 256, 256, 0, stream>>>(hsp, hs_b);

  // out projection + residual(x)
  gemm_bt<false, true, true, false><<<dim3(8, 64), 256, 0, stream>>>(
      hs_b, WoT, bo, x, tt, nullptr, MM, 1024, 128);
  ln_kernel<true><<<MM, 256, 0, stream>>>(tt, g1, be1, yy, yb);

  // FFN
  gemm_bt<true, false, false, true><<<dim3(32, 64), 256, 0, stream>>>(
      yb, W1T, bf1, nullptr, nullptr, hb, MM, FF, 1024);
  gemm_bt<false, true, true, false><<<dim3(8, 64), 256, 0, stream>>>(
      hb, W2T, bf2, yy, tt, nullptr, MM, DD, FF);
  ln_kernel<false><<<MM, 256, 0, stream>>>(tt, g2, be2, (float*)d_out, nullptr);
}

// Round 6
// 597.912 us; speedup vs baseline: 1.0931x; 1.0203x over previous
//
#include <hip/hip_runtime.h>
#include <hip/hip_bf16.h>
#include <stdint.h>

// Problem constants
#define DD 1024
#define AA 128
#define HH 8
#define FF 4096
#define BB 4
#define SS 2048
#define MM (BB*SS)      // 8192 tokens
#define EPSV 1e-5f

typedef __bf16 bf16x8 __attribute__((ext_vector_type(8)));
typedef __bf16 bf16x4 __attribute__((ext_vector_type(4)));
typedef float  f32x4  __attribute__((ext_vector_type(4)));
typedef float  f32x16 __attribute__((ext_vector_type(16)));

// ---------------- async global->LDS (16B per lane) ----------------
__device__ __forceinline__ void gload_lds16(const void* g, void* l) {
  __builtin_amdgcn_global_load_lds(
      (const __attribute__((address_space(1))) uint32_t*)(uintptr_t)g,
      (__attribute__((address_space(3))) uint32_t*)(uintptr_t)l, 16, 0, 0);
}

// ---------------- transpose + f32->bf16 convert: out[c][r] = in[r][c] ----------------
__global__ __launch_bounds__(256) void transpose_conv(const float* __restrict__ in,
                                                      __bf16* __restrict__ out,
                                                      int rows, int cols) {
  __shared__ float tile[64][65];
  const int r0 = blockIdx.y * 64, c0 = blockIdx.x * 64;
  for (int i = threadIdx.x; i < 4096; i += 256) {
    int r = i >> 6, c = i & 63;
    tile[r][c] = in[(long)(r0 + r) * cols + c0 + c];
  }
  __syncthreads();
  for (int i = threadIdx.x; i < 4096; i += 256) {
    int c = i >> 6, r = i & 63;
    out[(long)(c0 + c) * rows + r0 + r] = (__bf16)tile[r][c];
  }
}

// QKV weights: Wq/Wk/Wv are [H][D][A]; build WqkvT [3072][1024] (row n = p*1024+h*128+a, col d)
__global__ __launch_bounds__(256) void transpose_qkv(const float* __restrict__ Wq,
                                                     const float* __restrict__ Wk,
                                                     const float* __restrict__ Wv,
                                                     __bf16* __restrict__ out) {
  __shared__ float tile[64][65];
  const int z = blockIdx.z;
  const int p = z >> 3, h = z & 7;
  const float* in = ((p == 0) ? Wq : (p == 1) ? Wk : Wv) + (long)h * DD * AA;  // [D][A]
  __bf16* o = out + (long)(p * 1024 + h * 128) * DD;                           // [A][D]
  const int r0 = blockIdx.y * 64, c0 = blockIdx.x * 64;  // r over D, c over A
  for (int i = threadIdx.x; i < 4096; i += 256) {
    int r = i >> 6, c = i & 63;
    tile[r][c] = in[(long)(r0 + r) * AA + c0 + c];
  }
  __syncthreads();
  for (int i = threadIdx.x; i < 4096; i += 256) {
    int c = i >> 6, r = i & 63;
    o[(long)(c0 + c) * DD + r0 + r] = (__bf16)tile[r][c];
  }
}

// V columns of qkvb -> vTb [b*8+h][a][s], LDS-tiled, coalesced both sides
__global__ __launch_bounds__(256) void transpose_v(const __bf16* __restrict__ qkvb,
                                                   __bf16* __restrict__ vTb) {
  __shared__ float tile[64][65];
  const int s0 = blockIdx.x * 64, a0 = blockIdx.y * 64;
  const int bh = blockIdx.z, b = bh >> 3, h = bh & 7;
  const __bf16* src = qkvb + ((long)b * SS) * 3072 + 2048 + h * 128;
  for (int i = threadIdx.x; i < 4096; i += 256) {
    int r = i >> 6, c = i & 63;   // r: s, c: a
    tile[r][c] = (float)src[(long)(s0 + r) * 3072 + a0 + c];
  }
  __syncthreads();
  __bf16* dst = vTb + ((long)bh * 128) * 2048;
  for (int i = threadIdx.x; i < 4096; i += 256) {
    int c = i >> 6, r = i & 63;   // consecutive threads -> consecutive s
    dst[(long)(a0 + c) * 2048 + s0 + r] = (__bf16)tile[r][c];
  }
}

__global__ void build_qkv_bias(const float* __restrict__ bq, const float* __restrict__ bk,
                               const float* __restrict__ bv, float* __restrict__ out) {
  int i = blockIdx.x * 256 + threadIdx.x;
  if (i < 3072) {
    const float* src = (i < 1024) ? bq : (i < 2048) ? bk : bv;
    out[i] = src[i & 1023];
  }
}

__global__ void conv_f32_bf16(const float* __restrict__ in, __bf16* __restrict__ out, int n4) {
  int i = blockIdx.x * 256 + threadIdx.x;
  if (i < n4) {
    float4 v = ((const float4*)in)[i];
    bf16x4 o = { (__bf16)v.x, (__bf16)v.y, (__bf16)v.z, (__bf16)v.w };
    ((bf16x4*)out)[i] = o;
  }
}

// ---------------- generic GEMM (128x128, m97 structure): C = A * Bt^T + bias ------------
template<bool RELU, bool RESID, bool OUTF, bool OUTB>
__global__ __launch_bounds__(256) void gemm_bt(
    const __bf16* __restrict__ Ag, const __bf16* __restrict__ Bt,
    const float* __restrict__ bias, const float* __restrict__ resid,
    float* __restrict__ Cf, __bf16* __restrict__ Cb,
    int M, int N, int K)
{
  __shared__ __bf16 As[128 * 32];
  __shared__ __bf16 Bs[128 * 32];
  const int t = threadIdx.x;
  const int w = t >> 6, l = t & 63;
  const int gx = gridDim.x, nwg = gx * gridDim.y;
  int bid = blockIdx.y * gx + blockIdx.x;
  int swz = (bid & 7) * (nwg >> 3) + (bid >> 3);
  const int m0 = (swz / gx) * 128, n0 = (swz % gx) * 128;
  const int wr = w >> 1, wc = w & 1;
  const int lr = l & 15, lg = l >> 4;

  f32x4 acc[4][4] = {};

  const __bf16* gA = Ag + (long)(m0 + w * 32 + (l >> 2)) * K + (l & 3) * 8;
  const __bf16* gB = Bt + (long)(n0 + w * 32 + (l >> 2)) * K + (l & 3) * 8;
  __bf16* lA = &As[w * 1024];
  __bf16* lB = &Bs[w * 1024];

  for (int k0 = 0; k0 < K; k0 += 32) {
    gload_lds16(gA + k0, lA);
    gload_lds16(gA + (long)16 * K + k0, lA + 512);
    gload_lds16(gB + k0, lB);
    gload_lds16(gB + (long)16 * K + k0, lB + 512);
    __syncthreads();
    bf16x8 af[4], bfr[4];
#pragma unroll
    for (int mi = 0; mi < 4; mi++)
      af[mi] = *(const bf16x8*)&As[(wr * 64 + mi * 16 + lr) * 32 + lg * 8];
#pragma unroll
    for (int nj = 0; nj < 4; nj++)
      bfr[nj] = *(const bf16x8*)&Bs[(wc * 64 + nj * 16 + lr) * 32 + lg * 8];
#pragma unroll
    for (int mi = 0; mi < 4; mi++)
#pragma unroll
      for (int nj = 0; nj < 4; nj++)
        acc[mi][nj] = __builtin_amdgcn_mfma_f32_16x16x32_bf16(af[mi], bfr[nj], acc[mi][nj], 0, 0, 0);
    __syncthreads();
  }

#pragma unroll
  for (int mi = 0; mi < 4; mi++) {
    const int row0 = m0 + wr * 64 + mi * 16 + lg * 4;
#pragma unroll
    for (int nj = 0; nj < 4; nj++) {
      const int col = n0 + wc * 64 + nj * 16 + lr;
      const float bv = bias[col];
#pragma unroll
      for (int rg = 0; rg < 4; rg++) {
        const int row = row0 + rg;
        float v = acc[mi][nj][rg] + bv;
        if constexpr (RESID) v += resid[(long)row * N + col];
        if constexpr (RELU)  v = fmaxf(v, 0.f);
        if constexpr (OUTF)  Cf[(long)row * N + col] = v;
        if constexpr (OUTB)  Cb[(long)row * N + col] = (__bf16)v;
      }
    }
  }
}

// ---------------- 256x256 8-wave GEMM, BK=64, counted-vmcnt pipeline (T2+T3+T4+T5) ------
// Phases per K-tile: phase p computes mi-pair p (16 MFMA); B-frags read once (phase 0).
// Staging: iter kt stages A(kt+1) phases 0-1 (buf n) and B(kt+2) phases 1-2 (buf c: its B
// region is dead after phase 0). One s_waitcnt vmcnt(4) per K-tile (phase 3) keeps B(kt+2)'s
// 4 issues in flight across the barrier. LDS XOR-swizzle (r&7)<<4 on 16B granules, both sides.
template<bool RELU>
__global__ __launch_bounds__(512, 2) void gemm256(
    const __bf16* __restrict__ Ag, const __bf16* __restrict__ Bt,
    const float* __restrict__ bias, __bf16* __restrict__ Cb,
    int M, int N, int K)
{
  __shared__ __bf16 As[2][256 * 64];
  __shared__ __bf16 Bs[2][256 * 64];
  const int t = threadIdx.x, w = t >> 6, l = t & 63;
  const int gx = gridDim.x, nwg = gx * gridDim.y;
  int bid = blockIdx.y * gx + blockIdx.x;
  int swz = (bid & 7) * (nwg >> 3) + (bid >> 3);
  const int m0 = (swz / gx) * 256, n0 = (swz % gx) * 256;
  const int wr = w >> 2, wc = w & 3;       // 2 M-groups x 4 N-groups
  const int lr = l & 15, lg = l >> 4;
  const int NK = K / 64;

  f32x4 acc[8][4] = {};

  // staging: half-tile = 128 rows x 64 cols; wave w covers 16 rows = 2 issues x 8 rows.
  const int srow = l >> 3;                 // lane row within 8-row chunk
  const int sg = l & 7;                    // lane dest granule (16B)

#define STAGE_A(BUF, KT, HALF)                                                          \
  {                                                                                     \
    _Pragma("unroll")                                                                   \
    for (int j = 0; j < 2; j++) {                                                       \
      const int r0 = (HALF) * 128 + w * 16 + j * 8;                                     \
      const int r = r0 + srow;                                                          \
      const int gs = sg ^ (r & 7);                                                      \
      gload_lds16(Ag + (long)(m0 + r) * K + (KT) * 64 + gs * 8,                         \
                  (char*)As[BUF] + r0 * 128);                                           \
    }                                                                                   \
  }
#define STAGE_B(BUF, KT, HALF)                                                          \
  {                                                                                     \
    _Pragma("unroll")                                                                   \
    for (int j = 0; j < 2; j++) {                                                       \
      const int r0 = (HALF) * 128 + w * 16 + j * 8;                                     \
      const int r = r0 + srow;                                                          \
      const int gs = sg ^ (r & 7);                                                      \
      gload_lds16(Bt + (long)(n0 + r) * K + (KT) * 64 + gs * 8,                         \
                  (char*)Bs[BUF] + r0 * 128);                                           \
    }                                                                                   \
  }

  // prologue: A(0),B(0) -> buf0; B(1) -> buf1; wait oldest 8 (A0,B0) done.
  STAGE_A(0, 0, 0); STAGE_A(0, 0, 1);
  STAGE_B(0, 0, 0); STAGE_B(0, 0, 1);
  STAGE_B(1, 1, 0); STAGE_B(1, 1, 1);
  asm volatile("s_waitcnt vmcnt(4)" ::: "memory");
  __builtin_amdgcn_sched_barrier(0);
  __builtin_amdgcn_s_barrier();

  for (int kt = 0; kt < NK; kt++) {
    const int c = kt & 1, nb = c ^ 1;
    const char* Ab = (const char*)As[c];
    const char* Bb = (const char*)Bs[c];
    bf16x8 bfr[4][2];
    bf16x8 af[2][2];

#pragma unroll
    for (int ph = 0; ph < 4; ph++) {
      // ---- stage issues (targets' last readers finished >=1 barrier ago)
      if (ph == 0) { if (kt + 1 < NK) STAGE_A(nb, kt + 1, 0); }
      if (ph == 1) {
        if (kt + 1 < NK) STAGE_A(nb, kt + 1, 1);
        if (kt + 2 < NK) STAGE_B(c, kt + 2, 0);
      }
      if (ph == 2) { if (kt + 2 < NK) STAGE_B(c, kt + 2, 1); }

      // ---- ds_read register subtile (swizzled)
      if (ph == 0) {
#pragma unroll
        for (int nj = 0; nj < 4; nj++)
#pragma unroll
          for (int kh = 0; kh < 2; kh++) {
            const int r = wc * 64 + nj * 16 + lr;
            bfr[nj][kh] = *(const bf16x8*)(Bb + r * 128 + (((kh * 4 + lg) ^ (r & 7)) << 4));
          }
      }
#pragma unroll
      for (int mi2 = 0; mi2 < 2; mi2++)
#pragma unroll
        for (int kh = 0; kh < 2; kh++) {
          const int r = wr * 128 + (ph * 2 + mi2) * 16 + lr;
          af[mi2][kh] = *(const bf16x8*)(Ab + r * 128 + (((kh * 4 + lg) ^ (r & 7)) << 4));
        }

      asm volatile("s_waitcnt lgkmcnt(0)" ::: "memory");
      __builtin_amdgcn_sched_barrier(0);

      // ---- 16 MFMA (mi-pair x 4 nj x 2 kh)
      __builtin_amdgcn_s_setprio(1);
#pragma unroll
      for (int mi2 = 0; mi2 < 2; mi2++) {
        const int mi = ph * 2 + mi2;
#pragma unroll
        for (int nj = 0; nj < 4; nj++)
#pragma unroll
          for (int kh = 0; kh < 2; kh++)
            acc[mi][nj] = __builtin_amdgcn_mfma_f32_16x16x32_bf16(af[mi2][kh], bfr[nj][kh],
                                                                  acc[mi][nj], 0, 0, 0);
      }
      __builtin_amdgcn_s_setprio(0);

      if (ph == 3) {  // counted wait: all of kt+1 complete; B(kt+2) stays in flight
        asm volatile("s_waitcnt vmcnt(4)" ::: "memory");
        __builtin_amdgcn_sched_barrier(0);
      }
      __builtin_amdgcn_s_barrier();
    }
  }
#undef STAGE_A
#undef STAGE_B

  // ---- epilogue: bias (+ReLU) -> bf16
#pragma unroll
  for (int mi = 0; mi < 8; mi++) {
    const int row0 = m0 + wr * 128 + mi * 16 + lg * 4;
#pragma unroll
    for (int nj = 0; nj < 4; nj++) {
      const int col = n0 + wc * 64 + nj * 16 + lr;
      const float bv = bias[col];
#pragma unroll
      for (int rg = 0; rg < 4; rg++) {
        float v = acc[mi][nj][rg] + bv;
        if constexpr (RELU) v = fmaxf(v, 0.f);
        Cb[(long)(row0 + rg) * N + col] = (__bf16)v;
      }
    }
  }
}

// ---------------- flash attention: swapped-operand 32x32 MFMA, in-register softmax ----
__global__ __launch_bounds__(256) void attn_kernel(
    const __bf16* __restrict__ qkv,   // [8192][3072]  (q | k | v per head)
    const __bf16* __restrict__ vT,    // [B*H*128][2048]
    float* __restrict__ hsp)          // [H][8192][128] fp32 partials
{
  __shared__ __bf16 Ks[2][64 * 128];    // [kv][k], granule XOR (r&15)
  __shared__ __bf16 Vs[2][128 * 64];    // [a][kv], granule XOR (a&7)
  const int t = threadIdx.x, w = t >> 6, l = t & 63;
  const int q32 = l & 31, hi = l >> 5;
  const int h = blockIdx.y, b = blockIdx.z;
  const long rowbase = (long)b * SS + blockIdx.x * 128 + w * 32;
  const float C2 = (float)(0.08838834764831845 * 1.44269504088896340);  // inv_sqrt(128)*log2(e)

  const __bf16* kbase = qkv + (long)b * SS * 3072 + 1024 + h * 128;
  const __bf16* vbase = vT + ((long)(b * 8 + h) * 128) * 2048;

  bf16x8 qf[8];
  {
    const __bf16* qrow = qkv + (rowbase + q32) * 3072 + h * 128;
#pragma unroll
    for (int ks = 0; ks < 8; ks++) qf[ks] = *(const bf16x8*)(qrow + ks * 16 + hi * 8);
  }

  float mrun = -1e30f, lrun = 0.f;
  f32x16 O[4] = {};

#define STAGE(BUF, KV0)                                                              \
  {                                                                                  \
    _Pragma("unroll")                                                                \
    for (int i = 0; i < 4; i++) {                                                    \
      const int cb = (i * 4 + w) * 64;                                               \
      const int rK = (cb + l) >> 4, cK = l & 15;                                     \
      gload_lds16(kbase + (long)((KV0) + rK) * 3072 + ((cK ^ (rK & 15)) << 3),       \
                  (char*)Ks[BUF] + cb * 16);                                         \
      const int aV = (cb >> 3) + (l >> 3), cV = l & 7;                               \
      gload_lds16(vbase + (long)aV * 2048 + (KV0) + ((cV ^ (aV & 7)) << 3),          \
                  (char*)Vs[BUF] + cb * 16);                                         \
    }                                                                                \
  }

  STAGE(0, 0);
  __syncthreads();
  int cur = 0;

  for (int kt = 0; kt < 32; kt++) {
    if (kt < 31) STAGE(cur ^ 1, (kt + 1) * 64);

    f32x16 st[2] = {};
    __builtin_amdgcn_s_setprio(1);
#pragma unroll
    for (int s2 = 0; s2 < 2; s2++) {
      const int r = s2 * 32 + q32;
#pragma unroll
      for (int ks = 0; ks < 8; ks++) {
        const int g = (2 * ks + hi) ^ (r & 15);
        bf16x8 kf = *(const bf16x8*)((const char*)Ks[cur] + r * 256 + (g << 4));
        st[s2] = __builtin_amdgcn_mfma_f32_32x32x16_bf16(kf, qf[ks], st[s2], 0, 0, 0);
      }
    }
    __builtin_amdgcn_s_setprio(0);

    float pmax = st[0][0];
#pragma unroll
    for (int s2 = 0; s2 < 2; s2++)
#pragma unroll
      for (int rg = 0; rg < 16; rg++) pmax = fmaxf(pmax, st[s2][rg]);
    pmax = fmaxf(pmax, __shfl_xor(pmax, 32));

    if (!__all(pmax - mrun <= 64.f)) {
      const float mnew = fmaxf(mrun, pmax);
      const float sscl = exp2f((mrun - mnew) * C2);
      lrun *= sscl;
      mrun = mnew;
      float ssb[16];
#pragma unroll
      for (int rg = 0; rg < 16; rg++)
        ssb[rg] = __shfl(sscl, (l & 32) + ((rg & 3) + 8 * (rg >> 2) + 4 * hi));
#pragma unroll
      for (int aj = 0; aj < 4; aj++)
#pragma unroll
        for (int rg = 0; rg < 16; rg++) O[aj][rg] *= ssb[rg];
    }

    float rsum = 0.f;
#pragma unroll
    for (int s2 = 0; s2 < 2; s2++)
#pragma unroll
      for (int rg = 0; rg < 16; rg++) {
        const float p = exp2f((st[s2][rg] - mrun) * C2);
        st[s2][rg] = p;
        rsum += p;
      }
    rsum += __shfl_xor(rsum, 32);
    lrun += rsum;

    __builtin_amdgcn_s_setprio(1);
#pragma unroll
    for (int c = 0; c < 4; c++) {
      const int sA = (2 * c) >> 2, tA = (2 * c) & 3;
      const int sB = (2 * c + 1) >> 2, tB = (2 * c + 1) & 3;
      uint32_t W01a, W23a, W01b, W23b;
      asm("v_cvt_pk_bf16_f32 %0, %1, %2" : "=v"(W01a) : "v"(st[sA][4*tA+0]), "v"(st[sA][4*tA+1]));
      asm("v_cvt_pk_bf16_f32 %0, %1, %2" : "=v"(W23a) : "v"(st[sA][4*tA+2]), "v"(st[sA][4*tA+3]));
      asm("v_cvt_pk_bf16_f32 %0, %1, %2" : "=v"(W01b) : "v"(st[sB][4*tB+0]), "v"(st[sB][4*tB+1]));
      asm("v_cvt_pk_bf16_f32 %0, %1, %2" : "=v"(W23b) : "v"(st[sB][4*tB+2]), "v"(st[sB][4*tB+3]));
      const uint32_t X01 = __shfl_xor(hi ? W01a : W01b, 32);
      const uint32_t X23 = __shfl_xor(hi ? W23a : W23b, 32);
      union { uint32_t u[4]; bf16x8 v; } pa;
      pa.u[0] = hi ? X01 : W01a;
      pa.u[1] = hi ? X23 : W23a;
      pa.u[2] = hi ? W01b : X01;
      pa.u[3] = hi ? W23b : X23;
#pragma unroll
      for (int aj = 0; aj < 4; aj++) {
        const int a = aj * 32 + q32;
        const int gv = (2 * c + hi) ^ (a & 7);
        bf16x8 vf = *(const bf16x8*)((const char*)Vs[cur] + a * 128 + (gv << 4));
        O[aj] = __builtin_amdgcn_mfma_f32_32x32x16_bf16(pa.v, vf, O[aj], 0, 0, 0);
      }
    }
    __builtin_amdgcn_s_setprio(0);

    __syncthreads();
    cur ^= 1;
  }
#undef STAGE

  const float invl = 1.f / lrun;
  float invb[16];
#pragma unroll
  for (int rg = 0; rg < 16; rg++)
    invb[rg] = __shfl(invl, (l & 32) + ((rg & 3) + 8 * (rg >> 2) + 4 * hi));
  float* ho = hsp + ((long)h * MM + rowbase) * AA;
#pragma unroll
  for (int aj = 0; aj < 4; aj++)
#pragma unroll
    for (int rg = 0; rg < 16; rg++) {
      const int qr = (rg & 3) + 8 * (rg >> 2) + 4 * hi;
      ho[(long)qr * AA + aj * 32 + q32] = O[aj][rg] * invb[rg];
    }
}

// ---------------- sum 8 per-head partials -> bf16 ----------------
__global__ __launch_bounds__(256) void reduce_heads(const float* __restrict__ hsp,
                                                    __bf16* __restrict__ out) {
  const long i = (long)blockIdx.x * 256 + threadIdx.x;
  const float4* p = (const float4*)hsp;
  float4 s = p[i];
#pragma unroll
  for (int h = 1; h < 8; h++) {
    float4 v = p[i + (long)h * (MM * AA / 4)];
    s.x += v.x; s.y += v.y; s.z += v.z; s.w += v.w;
  }
  bf16x4 o = { (__bf16)s.x, (__bf16)s.y, (__bf16)s.z, (__bf16)s.w };
  ((bf16x4*)out)[i] = o;
}

// ---------------- LayerNorm over D=1024 (one block per row) ----------------
template<bool WB>
__global__ __launch_bounds__(256) void ln_kernel(
    const float* __restrict__ in, const float* __restrict__ g, const float* __restrict__ be,
    float* __restrict__ outf, __bf16* __restrict__ outb)
{
  const int row = blockIdx.x, t = threadIdx.x;
  const float4 xv = *(const float4*)(in + (long)row * DD + t * 4);
  float s = xv.x + xv.y + xv.z + xv.w;
  float s2 = xv.x * xv.x + xv.y * xv.y + xv.z * xv.z + xv.w * xv.w;
#pragma unroll
  for (int off = 32; off >= 1; off >>= 1) {
    s += __shfl_down(s, off);
    s2 += __shfl_down(s2, off);
  }
  __shared__ float sm[4], sm2[4];
  __shared__ float mu_s, rs_s;
  const int wid = t >> 6;
  if ((t & 63) == 0) { sm[wid] = s; sm2[wid] = s2; }
  __syncthreads();
  if (t == 0) {
    float S = sm[0] + sm[1] + sm[2] + sm[3];
    float S2 = sm2[0] + sm2[1] + sm2[2] + sm2[3];
    float mu = S * (1.f / 1024.f);
    float var = S2 * (1.f / 1024.f) - mu * mu;
    mu_s = mu;
    rs_s = rsqrtf(var + EPSV);
  }
  __syncthreads();
  const float mu = mu_s, rs = rs_s;
  const float4 gv = *(const float4*)(g + t * 4);
  const float4 bv = *(const float4*)(be + t * 4);
  float o0 = (xv.x - mu) * rs * gv.x + bv.x;
  float o1 = (xv.y - mu) * rs * gv.y + bv.y;
  float o2 = (xv.z - mu) * rs * gv.z + bv.z;
  float o3 = (xv.w - mu) * rs * gv.w + bv.w;
  float4 ov = { o0, o1, o2, o3 };
  *(float4*)(outf + (long)row * DD + t * 4) = ov;
  if constexpr (WB) {
    bf16x4 ob = { (__bf16)o0, (__bf16)o1, (__bf16)o2, (__bf16)o3 };
    *(bf16x4*)(outb + (long)row * DD + t * 4) = ob;
  }
}

// ---------------- launch ----------------
extern "C" void kernel_launch(void* const* d_in, const int* in_sizes, int n_in,
                              void* d_out, int out_size, void* d_ws, size_t ws_size,
                              hipStream_t stream) {
  const float* x    = (const float*)d_in[0];
  const float* Wq   = (const float*)d_in[1];
  const float* bq   = (const float*)d_in[2];
  const float* Wk   = (const float*)d_in[3];
  const float* bk   = (const float*)d_in[4];
  const float* Wv   = (const float*)d_in[5];
  const float* bv   = (const float*)d_in[6];
  const float* Wo   = (const float*)d_in[7];
  const float* bo   = (const float*)d_in[8];
  const float* g1   = (const float*)d_in[9];
  const float* be1  = (const float*)d_in[10];
  const float* g2   = (const float*)d_in[11];
  const float* be2  = (const float*)d_in[12];
  const float* W1   = (const float*)d_in[13];
  const float* bf1  = (const float*)d_in[14];
  const float* W2   = (const float*)d_in[15];
  const float* bf2  = (const float*)d_in[16];

  const size_t MB = 1ull << 20;
  char* ws = (char*)d_ws;
  __bf16* WqkvT    = (__bf16*)(ws + 0);         // 6 MB   [3072][1024]
  float*  qkv_bias = (float*) (ws + 6 * MB);    // 12 KB
  __bf16* WoT      = (__bf16*)(ws + 7 * MB);    // 256 KB [1024][128]
  __bf16* W1T      = (__bf16*)(ws + 8 * MB);    // 8 MB   [4096][1024]
  __bf16* W2T      = (__bf16*)(ws + 16 * MB);   // 8 MB   [1024][4096]
  __bf16* xb       = (__bf16*)(ws + 24 * MB);   // 16 MB  [8192][1024]
  __bf16* qkvb     = (__bf16*)(ws + 40 * MB);   // 48 MB  [8192][3072]
  __bf16* vTb      = (__bf16*)(ws + 88 * MB);   // 16 MB  [4096][2048]
  float*  hsp      = (float*) (ws + 104 * MB);  // 32 MB  [8][8192][128] fp32 partials
  __bf16* hs_b     = (__bf16*)(ws + 136 * MB);  // 2 MB
  float*  tt       = (float*) (ws + 104 * MB);  // 32 MB  (overlays hsp; hsp dead before out-proj)
  float*  yy       = (float*) (ws + 140 * MB);  // 32 MB  (post-LN1 fp32)
  __bf16* yb       = (__bf16*)(ws + 172 * MB);  // 16 MB
  __bf16* hb       = (__bf16*)(ws + 24 * MB);   // 64 MB, overlays xb/qkvb (dead by FFN1)

  // weight prep
  transpose_qkv<<<dim3(2, 16, 24), 256, 0, stream>>>(Wq, Wk, Wv, WqkvT);
  build_qkv_bias<<<12, 256, 0, stream>>>(bq, bk, bv, qkv_bias);
  transpose_conv<<<dim3(16, 2), 256, 0, stream>>>(Wo, WoT, 128, 1024);
  transpose_conv<<<dim3(64, 16), 256, 0, stream>>>(W1, W1T, 1024, 4096);
  transpose_conv<<<dim3(16, 64), 256, 0, stream>>>(W2, W2T, 4096, 1024);
  conv_f32_bf16<<<8192, 256, 0, stream>>>(x, xb, MM * DD / 4);

  // QKV projection (256^2 pipelined), then V^T via coalesced transpose
  gemm256<false><<<dim3(12, 32), 512, 0, stream>>>(
      xb, WqkvT, qkv_bias, qkvb, MM, 3072, 1024);
  transpose_v<<<dim3(32, 2, 32), 256, 0, stream>>>(qkvb, vTb);

  // attention -> per-head partials, then reduce
  attn_kernel<<<dim3(16, 8, 4), 256, 0, stream>>>(qkvb, vTb, hsp);
  reduce_heads<<<MM * AA / 4 / 256, 256, 0, stream>>>(hsp, hs_b);

  // out projection + residual(x)
  gemm_bt<false, true, true, false><<<dim3(8, 64), 256, 0, stream>>>(
      hs_b, WoT, bo, x, tt, nullptr, MM, 1024, 128);
  ln_kernel<true><<<MM, 256, 0, stream>>>(tt, g1, be1, yy, yb);

  // FFN
  gemm256<true><<<dim3(16, 32), 512, 0, stream>>>(
      yb, W1T, bf1, hb, MM, FF, 1024);
  gemm_bt<false, true, true, false><<<dim3(8, 64), 256, 0, stream>>>(
      hb, W2T, bf2, yy, tt, nullptr, MM, DD, FF);
  ln_kernel<false><<<MM, 256, 0, stream>>>(tt, g2, be2, (float*)d_out, nullptr);
}